// Round 9
// baseline (25.242 us; speedup 1.0000x reference)
//
#include <hip/hip_runtime.h>
#include <hip/hip_fp16.h>
#include <math.h>

typedef _Float16 half8 __attribute__((ext_vector_type(8)));
typedef _Float16 half4 __attribute__((ext_vector_type(4)));
typedef float f32x4 __attribute__((ext_vector_type(4)));
typedef unsigned short u16x8 __attribute__((ext_vector_type(8)));

#define S_LEN 2048
#define NH 8
#define DH 64
#define HD 512               // NH*DH
#define BQ 128
#define WMAX 128
#define SPAN 384             // BQ + 2*WMAX
#define NT 512               // 8 waves
#define PANEL (S_LEN * DH)   // halves per (b,h) panel

// ---------- prepass: contiguous-row fp32 -> f16 panels --------------------
// K_ws[b][h][s][d]: 16B chunk c8 of row s stored at chunk (c8 ^ (s&7)).
// Vt_ws[b][h][d][s]: key-chunk kc of dim d stored at (kc&~7)|((kc&7)^(d&7)).
// Q_ws[b][h][s][d]: unswizzled, PRE-SCALED by 0.125*log2(e).
// Each block reads 16 full 2048B rows of K, V, Q (contiguous!) and scatters.
__global__ __launch_bounds__(256)
void swa_prep(const float* __restrict__ kg, const float* __restrict__ vg,
              const float* __restrict__ qg,
              unsigned short* __restrict__ kws, unsigned short* __restrict__ vtws,
              unsigned short* __restrict__ qws)
{
    __shared__ unsigned short Vl[16 * HD];   // 16 rows x 512 halves = 16 KB
    const int bid = blockIdx.x;              // 256 = b(2) * sb(128)
    const int b = bid >> 7, sb = bid & 127, s16 = sb * 16;
    const int t = threadIdx.x;

    const size_t inoff = ((size_t)b * S_LEN + s16) * HD;
    const float* kin = kg + inoff;
    const float* vin = vg + inoff;
    const float* qin = qg + inoff;
    const float qs = 0.18033688011112042f;   // 0.125 * log2(e)

    #pragma unroll
    for (int it = 0; it < 4; ++it) {
        const int task = t + it * 256;                 // 1024 tasks
        const int r = task >> 6, cr = task & 63, h = cr >> 3, c8 = cr & 7;
        const int s = s16 + r;
        {   // K
            const float* p = kin + (size_t)r * HD + cr * 8;
            const f32x4 f0 = *(const f32x4*)p, f1 = *(const f32x4*)(p + 4);
            half8 hv;
            #pragma unroll
            for (int e = 0; e < 4; ++e) { hv[e] = (_Float16)f0[e]; hv[4+e] = (_Float16)f1[e]; }
            *(half8*)&kws[((size_t)(b*NH+h)*S_LEN + s)*DH + ((c8 ^ (s & 7)) << 3)] = hv;
        }
        {   // Q (scaled, unswizzled)
            const float* p = qin + (size_t)r * HD + cr * 8;
            const f32x4 f0 = *(const f32x4*)p, f1 = *(const f32x4*)(p + 4);
            half8 hv;
            #pragma unroll
            for (int e = 0; e < 4; ++e) { hv[e] = (_Float16)(f0[e]*qs); hv[4+e] = (_Float16)(f1[e]*qs); }
            *(half8*)&qws[((size_t)(b*NH+h)*S_LEN + s)*DH + c8 * 8] = hv;
        }
        {   // V -> LDS linear
            const float* p = vin + (size_t)r * HD + cr * 8;
            const f32x4 f0 = *(const f32x4*)p, f1 = *(const f32x4*)(p + 4);
            half8 hv;
            #pragma unroll
            for (int e = 0; e < 4; ++e) { hv[e] = (_Float16)f0[e]; hv[4+e] = (_Float16)f1[e]; }
            *(half8*)&Vl[r * HD + cr * 8] = hv;
        }
    }
    __syncthreads();
    #pragma unroll
    for (int it = 0; it < 4; ++it) {
        const int task = t + it * 256;                 // 1024: h(8) x d(64) x kc2(2)
        const int h = task >> 7, d = (task >> 1) & 63, kc2 = task & 1;
        u16x8 w;
        #pragma unroll
        for (int r = 0; r < 8; ++r) w[r] = Vl[(kc2 * 8 + r) * HD + h * DH + d];
        const int kc = (s16 >> 3) + kc2;
        const int swz = (kc & ~7) | ((kc & 7) ^ (d & 7));
        *(u16x8*)&vtws[((size_t)(b*NH+h)*DH + d) * S_LEN + swz * 8] = w;
    }
}

// ---------- attention: BQ=128, async staged from panels, 2-phase ----------
// Swapped QK^T: S^T = K*Q^T -> lane (c,g) holds 8 scores for query q0+16*wid+c.
// PV: O^T = V^T * P^T with K-axis permutation sigma(8g+e)=4g+(e&3)+16*(e>>2).
// V LDS is split into two half-tiles (rows of 192 keys) so each phase's image
// is LDS-contiguous for global_load_lds (wave-uniform base + lane*16 dest).
__global__ __launch_bounds__(NT, 1)
void swa_mfma(const unsigned short* __restrict__ qws,
              const unsigned short* __restrict__ kws,
              const unsigned short* __restrict__ vtws,
              const int* __restrict__ wptr, float* __restrict__ outg)
{
    __shared__ __align__(1024) unsigned short Kl[SPAN * DH];   // 48 KB [key][dim]
    __shared__ __align__(1024) unsigned short Va[DH * 192];    // 24 KB keys 0..191
    __shared__ __align__(1024) unsigned short Vb[DH * 192];    // 24 KB keys 192..383

    int W = *wptr; if (W > WMAX) W = WMAX;
    const int t = threadIdx.x;
    int bid = blockIdx.x;
    bid = (bid & 7) * (gridDim.x >> 3) + (bid >> 3);   // XCD-aware, 256 % 8 == 0
    const int qt = bid & 15, h = (bid >> 4) & 7, b = bid >> 7;
    const int i0 = qt * BQ, s0 = i0 - WMAX;            // fixed geometry (WMAX)

    const int wid = t >> 6, lane = t & 63, c = lane & 15, g = lane >> 4;
    const int q = i0 + wid * 16 + c;

    // Q: pre-scaled f16 panel rows (dense 128B rows)
    const unsigned short* qpan = qws + ((size_t)(b*NH+h)*S_LEN + q) * DH;
    const half8 qa0 = *(const half8*)(qpan + g * 8);
    const half8 qa1 = *(const half8*)(qpan + 32 + g * 8);

    const char* kpan = (const char*)(kws + (size_t)(b*NH+h) * PANEL);
    const char* vpan = (const char*)(vtws + (size_t)(b*NH+h) * PANEL);

    auto stageK = [&](int phase) {            // 24576 B per phase, linear dest
        #pragma unroll
        for (int it = 0; it < 3; ++it) {
            const int off = phase * 24576 + t * 16 + it * 8192;
            int srow = s0 + (off >> 7);
            srow = srow < 0 ? 0 : (srow > S_LEN - 1 ? S_LEN - 1 : srow);
            __builtin_amdgcn_global_load_lds(
                (const void*)(kpan + (size_t)srow * 128 + (off & 127)),
                (char*)Kl + off, 16, 0, 0);
        }
    };
    auto stageV = [&](int phase, unsigned short* vdst) {   // rows of 384 B
        #pragma unroll
        for (int it = 0; it < 3; ++it) {
            const int off = t * 16 + it * 8192;
            const int d = off / 384;
            const int cbyte = off - d * 384;
            int rb = s0 * 2 + phase * 384 + cbyte;
            rb = rb < 0 ? 0 : (rb > 4080 ? 4080 : rb);
            __builtin_amdgcn_global_load_lds(
                (const void*)(vpan + (size_t)d * 4096 + rb),
                (char*)vdst + off, 16, 0, 0);
        }
    };

    const int c7 = c & 7;
    const int ch0 = (g ^ c7) << 3;
    const int ch1 = ((g + 4) ^ c7) << 3;
    int lo = q - W; if (lo < 0) lo = 0;
    int hi = q + W; if (hi > S_LEN - 1) hi = S_LEN - 1;
    const unsigned rng = (unsigned)(hi - lo);
    const int qw0 = i0 + wid * 16;

    int ts = wid >> 1;
    const int ts0 = (s0 < 0) ? ((-s0) >> 5) : 0;
    if (ts0 > ts) ts = ts0;
    const int te_w = (16 * wid + 15 + 2 * WMAX) >> 5;
    const int te_s = (S_LEN - 1 - s0) >> 5;
    const int te = te_w < te_s ? te_w : te_s;

    float m = -1e4f, l = 0.f;
    f32x4 o0 = {0,0,0,0}, o1 = {0,0,0,0}, o2 = {0,0,0,0}, o3 = {0,0,0,0};

    auto computeTile = [&](int t32, const unsigned short* vbase, int cbloc) {
        // ---- QK^T (swapped): S^T = K * Q^T ----
        const unsigned short* krow = &Kl[(t32 * 32 + c) * 64];
        half8 k00 = *(const half8*)(krow + ch0);
        half8 k01 = *(const half8*)(krow + ch1);
        half8 k10 = *(const half8*)(krow + 16 * 64 + ch0);
        half8 k11 = *(const half8*)(krow + 16 * 64 + ch1);
        f32x4 st0 = {0,0,0,0}, st1 = {0,0,0,0};
        __builtin_amdgcn_s_setprio(1);
        st0 = __builtin_amdgcn_mfma_f32_16x16x32_f16(k00, qa0, st0, 0, 0, 0);
        st0 = __builtin_amdgcn_mfma_f32_16x16x32_f16(k01, qa1, st0, 0, 0, 0);
        st1 = __builtin_amdgcn_mfma_f32_16x16x32_f16(k10, qa0, st1, 0, 0, 0);
        st1 = __builtin_amdgcn_mfma_f32_16x16x32_f16(k11, qa1, st1, 0, 0, 0);
        __builtin_amdgcn_s_setprio(0);

        // ---- mask (interior fast path) + online softmax ----
        const int j0 = s0 + t32 * 32;
        float sv0[4], sv1[4];
        const bool allv = (j0 >= qw0 + 15 - W) && (j0 + 31 <= qw0 + W) &&
                          (j0 >= 0) && (j0 + 31 <= S_LEN - 1);
        if (allv) {
            #pragma unroll
            for (int r = 0; r < 4; ++r) { sv0[r] = st0[r]; sv1[r] = st1[r]; }
        } else {
            const int kb = j0 + 4 * g;
            #pragma unroll
            for (int r = 0; r < 4; ++r) {
                sv0[r] = ((unsigned)(kb + r - lo) <= rng)      ? st0[r] : -30000.f;
                sv1[r] = ((unsigned)(kb + 16 + r - lo) <= rng) ? st1[r] : -30000.f;
            }
        }
        float tmax = fmaxf(fmaxf(fmaxf(sv0[0], sv0[1]), fmaxf(sv0[2], sv0[3])),
                           fmaxf(fmaxf(sv1[0], sv1[1]), fmaxf(sv1[2], sv1[3])));
        tmax = fmaxf(tmax, __shfl_xor(tmax, 16));
        tmax = fmaxf(tmax, __shfl_xor(tmax, 32));
        if (__any(tmax > m)) {   // deferred rescale
            const float newm = fmaxf(m, tmax);
            const float alpha = exp2f(m - newm);
            m = newm;
            l *= alpha;
            o0 *= alpha; o1 *= alpha; o2 *= alpha; o3 *= alpha;
        }
        float p0[4], p1[4], ls = 0.f;
        #pragma unroll
        for (int r = 0; r < 4; ++r) {
            p0[r] = exp2f(sv0[r] - m);
            p1[r] = exp2f(sv1[r] - m);
            ls += p0[r] + p1[r];
        }
        l += ls;
        half8 pb;
        #pragma unroll
        for (int r = 0; r < 4; ++r) { pb[r] = (_Float16)p0[r]; pb[4+r] = (_Float16)p1[r]; }

        // ---- PV: O^T += V^T * P^T ----
        const int off1 = ((cbloc ^ c7) << 3) + ((g & 1) << 2);
        const int off2 = (((cbloc + 2) ^ c7) << 3) + ((g & 1) << 2);
        __builtin_amdgcn_s_setprio(1);
#define PV_STEP(DF, OACC) { \
        const unsigned short* vrow = vbase + (16 * DF + c) * 192; \
        half4 vlo = *(const half4*)(vrow + off1); \
        half4 vhi = *(const half4*)(vrow + off2); \
        half8 vf; \
        vf[0]=vlo[0]; vf[1]=vlo[1]; vf[2]=vlo[2]; vf[3]=vlo[3]; \
        vf[4]=vhi[0]; vf[5]=vhi[1]; vf[6]=vhi[2]; vf[7]=vhi[3]; \
        OACC = __builtin_amdgcn_mfma_f32_16x16x32_f16(vf, pb, OACC, 0, 0, 0); }
        PV_STEP(0, o0)
        PV_STEP(1, o1)
        PV_STEP(2, o2)
        PV_STEP(3, o3)
#undef PV_STEP
        __builtin_amdgcn_s_setprio(0);
    };

    // ---- staged pipeline: A-loads -> sync -> B-loads || compute A -> sync -> B ----
    stageK(0); stageV(0, Va);
    __syncthreads();                     // drains A (B not yet issued)
    stageK(1); stageV(1, Vb);            // B flies under phase-A compute

    for (int t32 = ts; t32 <= te && t32 < 6; ++t32)
        computeTile(t32, Va, 4 * t32 + (g >> 1));

    __syncthreads();                     // drains B

    for (int t32 = (ts > 6 ? ts : 6); t32 <= te; ++t32)
        computeTile(t32, Vb, 4 * (t32 - 6) + (g >> 1));

    // ---- epilogue ----
    l += __shfl_xor(l, 16);
    l += __shfl_xor(l, 32);
    const float inv = 1.0f / l;
    float* orow = outg + ((size_t)b * S_LEN + q) * HD + h * DH + 4 * g;
    { float4 w; w.x=o0[0]*inv; w.y=o0[1]*inv; w.z=o0[2]*inv; w.w=o0[3]*inv; *(float4*)(orow)      = w; }
    { float4 w; w.x=o1[0]*inv; w.y=o1[1]*inv; w.z=o1[2]*inv; w.w=o1[3]*inv; *(float4*)(orow + 16) = w; }
    { float4 w; w.x=o2[0]*inv; w.y=o2[1]*inv; w.z=o2[2]*inv; w.w=o2[3]*inv; *(float4*)(orow + 32) = w; }
    { float4 w; w.x=o3[0]*inv; w.y=o3[1]*inv; w.z=o3[2]*inv; w.w=o3[3]*inv; *(float4*)(orow + 48) = w; }
}

extern "C" void kernel_launch(void* const* d_in, const int* in_sizes, int n_in,
                              void* d_out, int out_size, void* d_ws, size_t ws_size,
                              hipStream_t stream) {
    const float* q = (const float*)d_in[0];
    const float* k = (const float*)d_in[1];
    const float* v = (const float*)d_in[2];
    const int*   w = (const int*)d_in[3];
    float* out = (float*)d_out;

    unsigned short* kws  = (unsigned short*)d_ws;              // 4.2 MB f16 K panels
    unsigned short* vtws = kws + (size_t)2 * NH * PANEL;       // 4.2 MB f16 V^T panels
    unsigned short* qws  = vtws + (size_t)2 * NH * PANEL;      // 4.2 MB f16 Q (scaled)

    swa_prep<<<dim3(256), dim3(256), 0, stream>>>(k, v, q, kws, vtws, qws);
    swa_mfma<<<dim3(256), dim3(NT), 0, stream>>>(qws, kws, vtws, w, out);
}

// Round 10
// 20.226 us; speedup vs baseline: 1.2480x; 1.2480x over previous
//
#include <hip/hip_runtime.h>
#include <hip/hip_fp16.h>
#include <math.h>

typedef _Float16 half8 __attribute__((ext_vector_type(8)));
typedef _Float16 half4 __attribute__((ext_vector_type(4)));
typedef __fp16 fp16x2 __attribute__((ext_vector_type(2)));
typedef float f32x4 __attribute__((ext_vector_type(4)));

#define S_LEN 2048
#define NH 8
#define DH 64
#define HD (NH*DH)
#define BQ 64
#define SPAN (BQ + 256)      // 320 keys staged per block (W<=128)
#define NT 256               // 4 waves; 80 KB LDS -> 2 blocks/CU

// Sliding-window attention, f16 MFMA flash kernel (R2 structure + tail trims).
// Swapped QK^T: S^T = K*Q^T -> lane (c,g) holds 8 scores for query q0+16*wid+c.
// PV: O^T = V^T * P^T with K-axis permutation sigma(8g+e)=4g+(e&3)+16*(e>>2)
// so the P fragment is the lane's own 8 probabilities (no repack).
// Trims vs R2: interior-tile mask skip (allv), K-fragment LDS reads software-
// pipelined one tile ahead (latency hidden under softmax VALU), pkrtz P-pack.
__global__ __launch_bounds__(NT, 2)
void swa_mfma(const float* __restrict__ qg, const float* __restrict__ kg,
              const float* __restrict__ vg, const int* __restrict__ wptr,
              float* __restrict__ outg)
{
    __shared__ __align__(16) unsigned short Kl[SPAN * DH];  // [key][dim] f16, 16B-chunk swizzle
    __shared__ __align__(16) unsigned short Vt[DH * SPAN];  // [dim][key] f16, 16B-chunk swizzle

    int W = *wptr; if (W > 128) W = 128;

    const int t = threadIdx.x;
    // XCD-aware bijective swizzle (gridDim.x = 512): each XCD's 64 contiguous
    // work-ids = all 32 q-tiles of 2 (b,h) panels -> K/V panels L2-shareable.
    int bid = blockIdx.x;
    bid = (bid & 7) * (gridDim.x >> 3) + (bid >> 3);
    const int qt = bid & 31, h = (bid >> 5) & 7, b = bid >> 8;
    const int i0 = qt * BQ, s0 = i0 - W;

    const float* kbh = kg + (size_t)b * S_LEN * HD + h * DH;
    const float* vbh = vg + (size_t)b * S_LEN * HD + h * DH;

    const int wid = t >> 6, lane = t & 63, c = lane & 15, g = lane >> 4;
    const int q = i0 + wid * 16 + c;

    // ---- Q loads issued first (overlap with staging) ----
    const float* qrow = qg + (size_t)b * S_LEN * HD + h * DH + (size_t)q * HD;
    const f32x4 qf0 = *(const f32x4*)(qrow + g * 8);
    const f32x4 qf1 = *(const f32x4*)(qrow + g * 8 + 4);
    const f32x4 qf2 = *(const f32x4*)(qrow + 32 + g * 8);
    const f32x4 qf3 = *(const f32x4*)(qrow + 32 + g * 8 + 4);

    // ---- stage K: rows [key][64] f16, chunk cr of row koff at (cr ^ (koff&7)) ----
    #pragma unroll
    for (int it = 0; it < 10; ++it) {               // 320*8/256 = 10 clean iters
        const int task = t + it * NT;
        const int koff = task >> 3, cr = task & 7;
        const int j = s0 + koff;
        f32x4 f0 = {0,0,0,0}, f1 = {0,0,0,0};
        if ((unsigned)j < S_LEN) {
            const float* p = kbh + (size_t)j * HD + cr * 8;
            f0 = *(const f32x4*)p; f1 = *(const f32x4*)(p + 4);
        }
        half8 hv;
        #pragma unroll
        for (int e = 0; e < 4; ++e) { hv[e] = (_Float16)f0[e]; hv[4+e] = (_Float16)f1[e]; }
        *(half8*)(&Kl[koff * 64 + ((cr ^ (koff & 7)) << 3)]) = hv;
    }
    // ---- stage V^T: 80 kq * 16 dq = 1280 tasks, 5 clean iters ----
    #pragma unroll
    for (int it = 0; it < 5; ++it) {
        const int task = t + it * NT;
        const int kq = task >> 4, dq = task & 15;
        f32x4 r[4];
        #pragma unroll
        for (int jj = 0; jj < 4; ++jj) {
            const int j = s0 + kq * 4 + jj;
            f32x4 f = {0,0,0,0};
            if ((unsigned)j < S_LEN) f = *(const f32x4*)(vbh + (size_t)j * HD + dq * 4);
            r[jj] = f;
        }
        #pragma unroll
        for (int i = 0; i < 4; ++i) {
            const int dim = dq * 4 + i;
            half4 w = { (_Float16)r[0][i], (_Float16)r[1][i],
                        (_Float16)r[2][i], (_Float16)r[3][i] };
            *(half4*)(&Vt[dim * SPAN + (((kq >> 1) ^ (dim & 7)) << 3) + ((kq & 1) << 2)]) = w;
        }
    }

    // ---- Q fragments (1/sqrt(D)*log2(e) folded; exp -> exp2 domain) ----
    half8 qa0, qa1;
    {
        const float qs = 0.18033688011112042f;  // 0.125 * log2(e)
        #pragma unroll
        for (int e = 0; e < 4; ++e) {
            qa0[e] = (_Float16)(qf0[e] * qs); qa0[4+e] = (_Float16)(qf1[e] * qs);
            qa1[e] = (_Float16)(qf2[e] * qs); qa1[4+e] = (_Float16)(qf3[e] * qs);
        }
    }

    const int c7 = c & 7;
    const int ch0 = (g ^ c7) << 3;
    const int ch1 = ((g + 4) ^ c7) << 3;
    int lo = q - W; if (lo < 0) lo = 0;
    int hi = q + W; if (hi > S_LEN - 1) hi = S_LEN - 1;
    const unsigned rng = (unsigned)(hi - lo);
    const int qw0 = i0 + wid * 16;

    int ts = wid >> 1;
    const int ts0 = (s0 < 0) ? ((-s0) >> 5) : 0;
    if (ts0 > ts) ts = ts0;
    const int te_w = (16 * wid + 15 + 2 * W) >> 5;
    const int te_s = (S_LEN - 1 - s0) >> 5;
    const int te = te_w < te_s ? te_w : te_s;

    float m = -1e4f, l = 0.f;
    f32x4 o0 = {0,0,0,0}, o1 = {0,0,0,0}, o2 = {0,0,0,0}, o3 = {0,0,0,0};

    auto loadKfrag = [&](int t32, half8 (&kf)[4]) {
        const unsigned short* krow = &Kl[(t32 * 32 + c) * 64];
        kf[0] = *(const half8*)(krow + ch0);
        kf[1] = *(const half8*)(krow + ch1);
        kf[2] = *(const half8*)(krow + 16 * 64 + ch0);
        kf[3] = *(const half8*)(krow + 16 * 64 + ch1);
    };

    auto computeTile = [&](int t32, half8 (&kf)[4]) {
        // ---- QK^T (swapped): S^T = K * Q^T ----
        f32x4 st0 = {0,0,0,0}, st1 = {0,0,0,0};
        __builtin_amdgcn_s_setprio(1);
        st0 = __builtin_amdgcn_mfma_f32_16x16x32_f16(kf[0], qa0, st0, 0, 0, 0);
        st0 = __builtin_amdgcn_mfma_f32_16x16x32_f16(kf[1], qa1, st0, 0, 0, 0);
        st1 = __builtin_amdgcn_mfma_f32_16x16x32_f16(kf[2], qa0, st1, 0, 0, 0);
        st1 = __builtin_amdgcn_mfma_f32_16x16x32_f16(kf[3], qa1, st1, 0, 0, 0);
        __builtin_amdgcn_s_setprio(0);

        // ---- mask (interior fast path) + online softmax (lane-local) ----
        const int j0 = s0 + t32 * 32;
        float sv0[4], sv1[4];
        const bool allv = (j0 >= qw0 + 15 - W) && (j0 + 31 <= qw0 + W) &&
                          (j0 >= 0) && (j0 + 31 <= S_LEN - 1);
        if (allv) {
            #pragma unroll
            for (int r = 0; r < 4; ++r) { sv0[r] = st0[r]; sv1[r] = st1[r]; }
        } else {
            const int kb = j0 + 4 * g;
            #pragma unroll
            for (int r = 0; r < 4; ++r) {
                sv0[r] = ((unsigned)(kb + r - lo) <= rng)      ? st0[r] : -30000.f;
                sv1[r] = ((unsigned)(kb + 16 + r - lo) <= rng) ? st1[r] : -30000.f;
            }
        }
        float tmax = fmaxf(fmaxf(fmaxf(sv0[0], sv0[1]), fmaxf(sv0[2], sv0[3])),
                           fmaxf(fmaxf(sv1[0], sv1[1]), fmaxf(sv1[2], sv1[3])));
        tmax = fmaxf(tmax, __shfl_xor(tmax, 16));
        tmax = fmaxf(tmax, __shfl_xor(tmax, 32));
        if (__any(tmax > m)) {   // deferred rescale
            const float newm = fmaxf(m, tmax);
            const float alpha = exp2f(m - newm);
            m = newm;
            l *= alpha;
            o0 *= alpha; o1 *= alpha; o2 *= alpha; o3 *= alpha;
        }
        float p0[4], p1[4], ls = 0.f;
        #pragma unroll
        for (int r = 0; r < 4; ++r) {
            p0[r] = exp2f(sv0[r] - m);
            p1[r] = exp2f(sv1[r] - m);
            ls += p0[r] + p1[r];
        }
        l += ls;
        // pkrtz P pack: slots [p0[0..3], p1[0..3]]
        fp16x2 pk0 = __builtin_amdgcn_cvt_pkrtz(p0[0], p0[1]);
        fp16x2 pk1 = __builtin_amdgcn_cvt_pkrtz(p0[2], p0[3]);
        fp16x2 pk2 = __builtin_amdgcn_cvt_pkrtz(p1[0], p1[1]);
        fp16x2 pk3 = __builtin_amdgcn_cvt_pkrtz(p1[2], p1[3]);
        half8 pb;
        pb[0]=(_Float16)pk0[0]; pb[1]=(_Float16)pk0[1]; pb[2]=(_Float16)pk1[0]; pb[3]=(_Float16)pk1[1];
        pb[4]=(_Float16)pk2[0]; pb[5]=(_Float16)pk2[1]; pb[6]=(_Float16)pk3[0]; pb[7]=(_Float16)pk3[1];

        // ---- PV: O^T += V^T * P^T ----
        const int cb = 4 * t32 + (g >> 1);
        const int off1 = ((cb ^ c7) << 3) + ((g & 1) << 2);
        const int off2 = (((cb + 2) ^ c7) << 3) + ((g & 1) << 2);
        __builtin_amdgcn_s_setprio(1);
#define PV_STEP(DF, OACC) { \
        const unsigned short* vrow = &Vt[(16 * DF + c) * SPAN]; \
        half4 vlo = *(const half4*)(vrow + off1); \
        half4 vhi = *(const half4*)(vrow + off2); \
        half8 vf; \
        vf[0]=vlo[0]; vf[1]=vlo[1]; vf[2]=vlo[2]; vf[3]=vlo[3]; \
        vf[4]=vhi[0]; vf[5]=vhi[1]; vf[6]=vhi[2]; vf[7]=vhi[3]; \
        OACC = __builtin_amdgcn_mfma_f32_16x16x32_f16(vf, pb, OACC, 0, 0, 0); }
        PV_STEP(0, o0)
        PV_STEP(1, o1)
        PV_STEP(2, o2)
        PV_STEP(3, o3)
#undef PV_STEP
        __builtin_amdgcn_s_setprio(0);
    };

    __syncthreads();   // K/V tiles ready (single barrier)

    // ---- tile loop, K-fragment LDS reads pipelined one tile ahead ----
    half8 kfA[4], kfB[4];
    loadKfrag(ts, kfA);
    int t32 = ts;
    while (t32 <= te) {
        if (t32 < te) loadKfrag(t32 + 1, kfB);
        computeTile(t32, kfA);
        ++t32;
        if (t32 > te) break;
        if (t32 < te) loadKfrag(t32 + 1, kfA);
        computeTile(t32, kfB);
        ++t32;
    }

    // ---- epilogue ----
    l += __shfl_xor(l, 16);
    l += __shfl_xor(l, 32);
    const float inv = 1.0f / l;
    float* orow = outg + (size_t)b * S_LEN * HD + h * DH + (size_t)q * HD + 4 * g;
    { float4 w; w.x=o0[0]*inv; w.y=o0[1]*inv; w.z=o0[2]*inv; w.w=o0[3]*inv; *(float4*)(orow)      = w; }
    { float4 w; w.x=o1[0]*inv; w.y=o1[1]*inv; w.z=o1[2]*inv; w.w=o1[3]*inv; *(float4*)(orow + 16) = w; }
    { float4 w; w.x=o2[0]*inv; w.y=o2[1]*inv; w.z=o2[2]*inv; w.w=o2[3]*inv; *(float4*)(orow + 32) = w; }
    { float4 w; w.x=o3[0]*inv; w.y=o3[1]*inv; w.z=o3[2]*inv; w.w=o3[3]*inv; *(float4*)(orow + 48) = w; }
}

extern "C" void kernel_launch(void* const* d_in, const int* in_sizes, int n_in,
                              void* d_out, int out_size, void* d_ws, size_t ws_size,
                              hipStream_t stream) {
    const float* q = (const float*)d_in[0];
    const float* k = (const float*)d_in[1];
    const float* v = (const float*)d_in[2];
    const int*   w = (const int*)d_in[3];
    float* out = (float*)d_out;

    const int nblocks = 2 * NH * (S_LEN / BQ);   // 512
    swa_mfma<<<dim3(nblocks), dim3(NT), 0, stream>>>(q, k, v, w, out);
}